// Round 9
// baseline (267.437 us; speedup 1.0000x reference)
//
#include <hip/hip_runtime.h>
#include <hip/hip_bf16.h>

typedef __attribute__((ext_vector_type(8))) short short8;
typedef __attribute__((ext_vector_type(4))) float f32x4;
typedef __attribute__((ext_vector_type(4))) unsigned int u32x4;
typedef __attribute__((ext_vector_type(2))) unsigned int u32x2;

#define DIN  4096
#define DOUT 4096
#define NTOK 16384

static __device__ __forceinline__ unsigned short f2b(float f) {
  union { __hip_bfloat16 h; unsigned short u; } cv;
  cv.h = __float2bfloat16(f);
  return cv.u;
}

// ------------- prologue (merged): transpose+convert weights to bf16 ----------
// btt_r[n][b][k] f32 -> Rt[n][c=k][b] bf16 ; btt_l[m][j][a] f32 -> Lt[m][a][j]
__global__ __launch_bounds__(256) void prep(const float* __restrict__ r,
                                            const float* __restrict__ l,
                                            unsigned short* __restrict__ rt,
                                            unsigned short* __restrict__ lt) {
  __shared__ unsigned short tile[128 * 68];
  const int q = threadIdx.x;
  if (blockIdx.x < 64) {
    const int n = blockIdx.x;
#pragma unroll
    for (int it = 0; it < 8; ++it) {
      const int idx = q + it * 256;           // float4 units
      const int b = idx >> 5, k4 = idx & 31;
      const float4 v = *(const float4*)(r + (size_t)n * 8192 + b * 128 + k4 * 4);
      unsigned int lo = (unsigned)f2b(v.x) | ((unsigned)f2b(v.y) << 16);
      unsigned int hi = (unsigned)f2b(v.z) | ((unsigned)f2b(v.w) << 16);
      u32x2 pk = {lo, hi};
      *(u32x2*)((char*)tile + (b * 264 + k4 * 8)) = pk;   // [b][k] stride 132
    }
    __syncthreads();
#pragma unroll
    for (int it = 0; it < 32; ++it) {
      const int o = q + it * 256;             // o = c*64 + b
      const int c = o >> 6, b = o & 63;
      rt[(size_t)n * 8192 + o] = tile[b * 132 + c];
    }
  } else {
    const int m = blockIdx.x - 64;
#pragma unroll
    for (int it = 0; it < 8; ++it) {
      const int idx = q + it * 256;
      const int j = idx >> 4, a4 = idx & 15;
      const float4 v = *(const float4*)(l + (size_t)m * 8192 + j * 64 + a4 * 4);
      unsigned int lo = (unsigned)f2b(v.x) | ((unsigned)f2b(v.y) << 16);
      unsigned int hi = (unsigned)f2b(v.z) | ((unsigned)f2b(v.w) << 16);
      u32x2 pk = {lo, hi};
      *(u32x2*)((char*)tile + (j * 136 + a4 * 8)) = pk;   // [j][a] stride 68
    }
    __syncthreads();
#pragma unroll
    for (int it = 0; it < 32; ++it) {
      const int o = q + it * 256;             // o = a*128 + j
      const int a = o >> 7, j = o & 127;
      lt[(size_t)m * 8192 + o] = tile[j * 68 + a];
    }
  }
}

// ---------------- kernel1: stage1, coalesced LDS-staged, dbuf ----------------
// h layout: [tile16][n][c][t&15] bf16, tile16 = 0..1023
// grid (32 strips, 64 n); block 256 = 4 waves; strip = 512 tokens = 16 iters
// of 32 tokens. x staged coalesced (4 rows x 256B full lines per instr) into
// XOR-swizzled LDS; Rt register-resident (4 short8/wave); 1 barrier per iter.
// Two NAMED LDS buffers (disjoint objects -> compute ds_reads can schedule
// ahead of next stage's vmcnt wait).
__global__ __launch_bounds__(256) void k1(const float* __restrict__ x,
                                          const unsigned short* __restrict__ rt,
                                          unsigned short* __restrict__ hbuf) {
  __shared__ unsigned short xs0[32 * 64];     // [t][b] bf16, rows 128B, swizzled
  __shared__ unsigned short xs1[32 * 64];
  const int n = blockIdx.y, strip = blockIdx.x;
  const int tid = threadIdx.x, wave = tid >> 6, lane = tid & 63;
  const int l15 = lane & 15, l4 = lane >> 4;

  // Rt B-fragments: bf[ct2][kh]: c = (wave*2+ct2)*16+l15, b = kh*32+l4*8 ..+8
  short8 bf[2][2];
#pragma unroll
  for (int ct2 = 0; ct2 < 2; ++ct2)
#pragma unroll
    for (int kh = 0; kh < 2; ++kh)
      bf[ct2][kh] = *(const short8*)(rt + (size_t)n * 8192 +
                      ((wave * 2 + ct2) * 16 + l15) * 64 + kh * 32 + l4 * 8);

#define STAGE(IT, DST)                                                       \
  {                                                                          \
    _Pragma("unroll")                                                        \
    for (int rnd = 0; rnd < 2; ++rnd) {                                      \
      const int flat = rnd * 256 + tid;                                      \
      const int t = flat >> 4, c4 = flat & 15;                               \
      const float4 v = *(const float4*)(                                     \
          x + (size_t)(strip * 512 + (IT) * 32 + t) * DIN + n * 64 + c4 * 4);\
      unsigned int lo = (unsigned)f2b(v.x) | ((unsigned)f2b(v.y) << 16);     \
      unsigned int hi = (unsigned)f2b(v.z) | ((unsigned)f2b(v.w) << 16);     \
      u32x2 pk = {lo, hi};                                                   \
      *(u32x2*)((char*)DST + (t * 128 + ((c4 * 8) ^ ((t & 7) << 4)))) = pk;  \
    }                                                                        \
  }

#define COMPUTE(IT, SRC)                                                     \
  {                                                                          \
    _Pragma("unroll")                                                        \
    for (int tt = 0; tt < 2; ++tt) {                                         \
      const int t = tt * 16 + l15;                                           \
      const short8 a0 = *(const short8*)((char*)SRC +                        \
          (t * 128 + ((l4 * 16) ^ ((t & 7) << 4))));                         \
      const short8 a1 = *(const short8*)((char*)SRC +                        \
          (t * 128 + ((64 + l4 * 16) ^ ((t & 7) << 4))));                    \
      const int tile = strip * 32 + (IT) * 2 + tt;                           \
      _Pragma("unroll")                                                      \
      for (int ct2 = 0; ct2 < 2; ++ct2) {                                    \
        f32x4 acc = {0.f, 0.f, 0.f, 0.f};                                    \
        acc = __builtin_amdgcn_mfma_f32_16x16x32_bf16(a0, bf[ct2][0], acc, 0, 0, 0); \
        acc = __builtin_amdgcn_mfma_f32_16x16x32_bf16(a1, bf[ct2][1], acc, 0, 0, 0); \
        unsigned int lo = (unsigned)f2b(acc[0]) | ((unsigned)f2b(acc[1]) << 16);     \
        unsigned int hi = (unsigned)f2b(acc[2]) | ((unsigned)f2b(acc[3]) << 16);     \
        u32x2 pk = {lo, hi};                                                 \
        unsigned short* hb = hbuf + (size_t)(tile * 64 + n) * 2048 +         \
            ((wave * 2 + ct2) * 16 + l15) * 16 + l4 * 4;                     \
        *(u32x2*)hb = pk;                                                    \
      }                                                                      \
    }                                                                        \
  }

  STAGE(0, xs0)
  __syncthreads();
  for (int it2 = 0; it2 < 8; ++it2) {
    STAGE(2 * it2 + 1, xs1)
    COMPUTE(2 * it2, xs0)
    __syncthreads();
    if (it2 < 7) STAGE(2 * it2 + 2, xs0)
    COMPUTE(2 * it2 + 1, xs1)
    __syncthreads();
  }
#undef STAGE
#undef COMPUTE
}

// ---------------- kernel2: stage2, un-chunked, m-paired, dbuf ----------------
// block owns m-pair mp -> c in {4mp..4mp+3} = full 128B line per (tile,n)
// grid (32 strips, 32 mp); block 256 = 4 waves; strip = 512 tokens = 16 iters
__global__ __launch_bounds__(256) void k2(const unsigned short* __restrict__ hbuf,
                                          const unsigned short* __restrict__ lt,
                                          const float* __restrict__ bias,
                                          float* __restrict__ y) {
  __shared__ unsigned short as_[2][2][32 * 128];  // [buf][m_loc][t][j] swizzled
  const int mp = blockIdx.y;
  const int strip = blockIdx.x;
  const int tid = threadIdx.x;
  const int wave = tid >> 6, lane = tid & 63;
  const int l15 = lane & 15, l4 = lane >> 4;
  const int m_loc = wave & 1, ah = wave >> 1;
  const int m = mp * 2 + m_loc;

  // B-fragments: Lt[m][a][j=ks*32+l4*8..+8], a = ah*32 + at*16 + l15
  short8 bfr[2][4];
#pragma unroll
  for (int at = 0; at < 2; ++at)
#pragma unroll
    for (int ks = 0; ks < 4; ++ks)
      bfr[at][ks] = *(const short8*)(lt + (size_t)m * 8192 +
                      (ah * 32 + at * 16 + l15) * 128 + ks * 32 + l4 * 8);
  const float bv0 = bias[m * 64 + ah * 32 + l15];
  const float bv1 = bias[m * 64 + ah * 32 + 16 + l15];

  auto stage = [&](int it, int b) {
#pragma unroll
    for (int half = 0; half < 4; ++half) {
      const int idx = tid + half * 256;           // 0..1023 16B units
      const int sub8 = idx & 7, nn = (idx >> 3) & 63, tio = idx >> 9;
      const int tg16 = strip * 32 + it * 2 + tio;
      const u32x4 v = *(const u32x4*)(hbuf + (size_t)(tg16 * 64 + nn) * 2048 +
                                      mp * 64 + sub8 * 8);
      const int c_loc = sub8 >> 1, hh = sub8 & 1;
      const int j = nn * 2 + (c_loc & 1), ml = c_loc >> 1;
      char* base = (char*)as_ + ((b * 2 + ml) * 32) * 256;
#pragma unroll
      for (int e = 0; e < 8; ++e) {
        const unsigned int w = v[e >> 1];
        const unsigned short val = (e & 1) ? (unsigned short)(w >> 16)
                                           : (unsigned short)(w & 0xffff);
        const int t = tio * 16 + hh * 8 + e;
        *(unsigned short*)(base + t * 256 + ((j * 2) ^ ((t & 7) << 4))) = val;
      }
    }
  };

  stage(0, 0);
  __syncthreads();
  int buf = 0;
  for (int it = 0; it < 16; ++it) {
    if (it < 15) stage(it + 1, buf ^ 1);
    f32x4 acc00 = {0,0,0,0}, acc01 = {0,0,0,0}, acc10 = {0,0,0,0}, acc11 = {0,0,0,0};
    const char* abase = (char*)as_ + ((buf * 2 + m_loc) * 32) * 256;
#pragma unroll
    for (int th = 0; th < 2; ++th) {
      const int t = th * 16 + l15;
#pragma unroll
      for (int ks = 0; ks < 4; ++ks) {
        const short8 av = *(const short8*)(abase + t * 256 +
                            ((ks * 64 + l4 * 16) ^ ((t & 7) << 4)));
        if (th == 0) {
          acc00 = __builtin_amdgcn_mfma_f32_16x16x32_bf16(av, bfr[0][ks], acc00, 0, 0, 0);
          acc10 = __builtin_amdgcn_mfma_f32_16x16x32_bf16(av, bfr[1][ks], acc10, 0, 0, 0);
        } else {
          acc01 = __builtin_amdgcn_mfma_f32_16x16x32_bf16(av, bfr[0][ks], acc01, 0, 0, 0);
          acc11 = __builtin_amdgcn_mfma_f32_16x16x32_bf16(av, bfr[1][ks], acc11, 0, 0, 0);
        }
      }
    }
    const size_t t0 = (size_t)(strip * 512 + it * 32 + l4 * 4);
    float* y0 = y + (size_t)m * 64 + ah * 32 + l15;
#pragma unroll
    for (int jj = 0; jj < 4; ++jj) {
      y0[(t0 + jj) * DOUT]      = acc00[jj] + bv0;
      y0[(t0 + jj) * DOUT + 16] = acc10[jj] + bv1;
      y0[(t0 + 16 + jj) * DOUT]      = acc01[jj] + bv0;
      y0[(t0 + 16 + jj) * DOUT + 16] = acc11[jj] + bv1;
    }
    __syncthreads();
    buf ^= 1;
  }
}

extern "C" void kernel_launch(void* const* d_in, const int* in_sizes, int n_in,
                              void* d_out, int out_size, void* d_ws, size_t ws_size,
                              hipStream_t stream) {
  const float* x    = (const float*)d_in[0];
  const float* bl   = (const float*)d_in[1];
  const float* br   = (const float*)d_in[2];
  const float* bias = (const float*)d_in[3];
  float* y = (float*)d_out;

  unsigned short* rt   = (unsigned short*)d_ws;          // 1 MB
  unsigned short* ltw  = rt + 64 * 8192;                 // 1 MB
  unsigned short* hbuf = ltw + 64 * 8192;                // 268 MB

  prep<<<128, 256, 0, stream>>>(br, bl, rt, ltw);
  k1<<<dim3(32, 64), 256, 0, stream>>>(x, rt, hbuf);
  k2<<<dim3(32, 32), 256, 0, stream>>>(hbuf, ltw, bias, y);
}